// Round 12
// baseline (394.855 us; speedup 1.0000x reference)
//
#include <hip/hip_runtime.h>

#define N_NODES 131072
#define N_EDGES 2097152
#define N_GRAPHS 128
#define POOL_NPB 256       // nodes per block in k_pool
#define NB 256             // buckets (both src- and dst-binning)
#define BUCKET_SHIFT 9     // 512 nodes per bucket
#define BUCKET_CAP 9728    // max edges per bucket (mean 8192, +17 sigma)
#define BIN_EPT 32         // edges per thread per pass in k_bin (8192/block)

// ---------------- bucket cursor init ----------------
__global__ __launch_bounds__(256) void k_init_buckets(int* __restrict__ cursor_d,
                                                      int* __restrict__ cursor_s) {
  int i = threadIdx.x;
  cursor_d[i] = i * BUCKET_CAP;
  cursor_s[i] = i * BUCKET_CAP;
}

// ---------------- phase A: bin edges (two-pass, zero per-edge global atomics) ----
__global__ __launch_bounds__(256) void k_bin(const int* __restrict__ src,
                                             const int* __restrict__ dst,
                                             int* __restrict__ cursor_d,
                                             int* __restrict__ cursor_s,
                                             unsigned int* __restrict__ recs_d,
                                             unsigned short* __restrict__ recs_s) {
  __shared__ int hd[NB];
  __shared__ int hs[NB];
  const int t = threadIdx.x;
  const int e0 = blockIdx.x * (256 * BIN_EPT);
  hd[t] = 0; hs[t] = 0;
  __syncthreads();
#pragma unroll 4
  for (int k = 0; k < BIN_EPT; ++k) {
    int e = e0 + k * 256 + t;
    atomicAdd(&hd[dst[e] >> BUCKET_SHIFT], 1);
    atomicAdd(&hs[src[e] >> BUCKET_SHIFT], 1);
  }
  __syncthreads();
  { int c = hd[t]; hd[t] = c ? atomicAdd(&cursor_d[t], c) : 0; }
  { int c = hs[t]; hs[t] = c ? atomicAdd(&cursor_s[t], c) : 0; }
  __syncthreads();
#pragma unroll 4
  for (int k = 0; k < BIN_EPT; ++k) {
    int e = e0 + k * 256 + t;      // re-read (L2/L3 hot)
    int s = src[e];
    int d = dst[e];
    int pd = atomicAdd(&hd[d >> BUCKET_SHIFT], 1);
    recs_d[pd] = ((unsigned int)s << BUCKET_SHIFT) | (unsigned int)(d & 511);
    int ps = atomicAdd(&hs[s >> BUCKET_SHIFT], 1);
    recs_s[ps] = (unsigned short)(s & 511);
  }
}

// ---------------- outdeg via LDS histogram -> src_norm ----------------
__global__ __launch_bounds__(512) void k_outdeg(const unsigned short* __restrict__ recs_s,
                                                const int* __restrict__ cursor_s,
                                                float* __restrict__ src_norm) {
  __shared__ int hist[512];
  const int b = blockIdx.x;
  const int t = threadIdx.x;
  hist[t] = 0;
  __syncthreads();
  const int beg = b * BUCKET_CAP;
  const int end = cursor_s[b];
  for (int i = beg + t; i < end; i += 512) atomicAdd(&hist[recs_s[i]], 1);
  __syncthreads();
  int od = hist[t]; if (od < 1) od = 1;
  src_norm[b * 512 + t] = 1.0f / sqrtf((float)od);
}

// ---------------- bucket base: exclusive scan of dst-bucket counts ----------------
__global__ __launch_bounds__(256) void k_bucket_scan(const int* __restrict__ cursor_d,
                                                     int* __restrict__ bucket_base,
                                                     int* __restrict__ row_start) {
  __shared__ int tmp[256];
  int t = threadIdx.x;
  int c = cursor_d[t] - t * BUCKET_CAP;
  tmp[t] = c;
  __syncthreads();
  for (int off = 1; off < 256; off <<= 1) {
    int x = (t >= off) ? tmp[t - off] : 0;
    __syncthreads();
    tmp[t] += x;
    __syncthreads();
  }
  bucket_base[t] = tmp[t] - c;
  if (t == 0) row_start[N_NODES] = N_EDGES;
}

// ---------------- phase B: indeg+row_start+dst_norm+CSR fill, all in LDS --------
__global__ __launch_bounds__(512) void k_fill2(const unsigned int* __restrict__ recs_d,
                                               const int* __restrict__ cursor_d,
                                               const int* __restrict__ bucket_base,
                                               int* __restrict__ row_start,
                                               float* __restrict__ dst_norm,
                                               int* __restrict__ csr_src) {
  __shared__ int hist[512];
  __shared__ int lcur[512];
  const int b = blockIdx.x;
  const int t = threadIdx.x;
  hist[t] = 0;
  __syncthreads();
  const int beg = b * BUCKET_CAP;
  const int end = cursor_d[b];
  for (int i = beg + t; i < end; i += 512) atomicAdd(&hist[recs_d[i] & 511], 1);
  __syncthreads();
  int deg = hist[t];
  lcur[t] = deg;
  __syncthreads();
  for (int off = 1; off < 512; off <<= 1) {
    int x = (t >= off) ? lcur[t - off] : 0;
    __syncthreads();
    lcur[t] += x;
    __syncthreads();
  }
  int rs = bucket_base[b] + lcur[t] - deg;
  row_start[b * 512 + t] = rs;
  int dd = deg < 1 ? 1 : deg;
  dst_norm[b * 512 + t] = 1.0f / sqrtf((float)dd);
  lcur[t] = rs;
  __syncthreads();
  for (int i = beg + t; i < end; i += 512) {
    unsigned int r = recs_d[i];
    int p = atomicAdd(&lcur[r & 511], 1);
    csr_src[p] = (int)(r >> BUCKET_SHIFT);
  }
}

// ---------------- GEMM v6: 8x8 register tile -> 0.5 B/FLOP LDS ------------------
// ROWS=128, KC=32. Thread (tr,tc) computes 8 rows {tr*4..+3, 64+tr*4..+3} x TN
// cols. A-reads: two b128 within a 256B half-row span -> 2-way bank alias
// (free). B-reads: TN/4 b128 at wave-uniform-ish addrs (<=8 distinct) ->
// broadcast (free). Per kk: 32B A + TN*4B B for 8*TN FMA. Round-11's 4x4 tile
// was LDS-BW-bound at 1 B/FLOP (79us ~= 62us LDS floor); this halves it.
// No register prefetch (r8/r10: compiler balloons VGPR); plain barrier loop.
template <int DIN, int DOUT, int TN, int NTHR>
__global__ __launch_bounds__(NTHR) void k_gemm(const float* __restrict__ h,
                                               const float* __restrict__ src_norm,
                                               const float* __restrict__ W,
                                               float* __restrict__ out) {
  constexpr int KC   = 32;
  constexpr int ROWS = 128;
  constexpr int NCH  = DIN / KC;
  constexpr int HF4  = KC * ROWS / 4;   // float4s in h tile (1024)
  constexpr int WF4  = KC * DOUT / 4;   // float4s in W chunk
  __shared__ float hT[KC][ROWS];
  __shared__ float Ws[KC][DOUT];

  const int t  = threadIdx.x;
  const int rowBase = blockIdx.x * ROWS;
  const int tr = t & 15;
  const int tc = t >> 4;

  float acc[8][TN];
#pragma unroll
  for (int i = 0; i < 8; ++i)
#pragma unroll
    for (int j = 0; j < TN; ++j) acc[i][j] = 0.0f;

  for (int ch = 0; ch < NCH; ++ch) {
    const int kc = ch * KC;
    // stage hT (transposed, swizzled writes); pure copy, norm in epilogue
    for (int f = t; f < HF4; f += NTHR) {
      int rg = f >> 3;
      int ks = (f & 7) * 4;
      float4 v = *reinterpret_cast<const float4*>(&h[(size_t)(rowBase + rg) * DIN + kc + ks]);
      hT[ks + 0][rg ^ ((((ks + 0) >> 3) & 3) << 3)] = v.x;
      hT[ks + 1][rg ^ ((((ks + 1) >> 3) & 3) << 3)] = v.y;
      hT[ks + 2][rg ^ ((((ks + 2) >> 3) & 3) << 3)] = v.z;
      hT[ks + 3][rg ^ ((((ks + 3) >> 3) & 3) << 3)] = v.w;
    }
    // stage Ws (chunk rows are contiguous in W)
    for (int f = t; f < WF4; f += NTHR) {
      int idx = f * 4;
      *reinterpret_cast<float4*>(&Ws[0][0] + idx) =
          *reinterpret_cast<const float4*>(&W[(size_t)kc * DOUT + idx]);
    }
    __syncthreads();
#pragma unroll
    for (int kk = 0; kk < KC; ++kk) {
      const int swz = ((kk >> 3) & 3) << 3;
      float4 a0 = *reinterpret_cast<const float4*>(&hT[kk][(tr * 4) ^ swz]);
      float4 a1 = *reinterpret_cast<const float4*>(&hT[kk][64 + ((tr * 4) ^ swz)]);
      float bb[TN];
#pragma unroll
      for (int q = 0; q < TN / 4; ++q) {
        float4 b = *reinterpret_cast<const float4*>(&Ws[kk][tc * TN + q * 4]);
        bb[q * 4 + 0] = b.x; bb[q * 4 + 1] = b.y;
        bb[q * 4 + 2] = b.z; bb[q * 4 + 3] = b.w;
      }
      float av0[4] = {a0.x, a0.y, a0.z, a0.w};
      float av1[4] = {a1.x, a1.y, a1.z, a1.w};
#pragma unroll
      for (int i = 0; i < 4; ++i)
#pragma unroll
        for (int j = 0; j < TN; ++j) {
          acc[i][j]     += av0[i] * bb[j];
          acc[4 + i][j] += av1[i] * bb[j];
        }
    }
    __syncthreads();
  }

#pragma unroll
  for (int half = 0; half < 2; ++half) {
#pragma unroll
    for (int i = 0; i < 4; ++i) {
      int row = rowBase + half * 64 + tr * 4 + i;
      float nrm = src_norm[row];
      float* op = &out[(size_t)row * DOUT + tc * TN];
#pragma unroll
      for (int q = 0; q < TN / 4; ++q) {
        float4 v = {acc[half * 4 + i][q * 4 + 0] * nrm,
                    acc[half * 4 + i][q * 4 + 1] * nrm,
                    acc[half * 4 + i][q * 4 + 2] * nrm,
                    acc[half * 4 + i][q * 4 + 3] * nrm};
        *reinterpret_cast<float4*>(op + q * 4) = v;
      }
    }
  }
}

// ---------------- aggregation: float4 gathers, D/4 lanes per node ----------------
template <int D>
__global__ __launch_bounds__(256) void k_agg(const float* __restrict__ hw,
                                             const int* __restrict__ row_start,
                                             const int* __restrict__ csr_src,
                                             const float* __restrict__ dst_norm,
                                             const float* __restrict__ bias,
                                             float* __restrict__ out) {
  constexpr int LPN = D / 4;     // lanes per node
  constexpr int NPW = 64 / LPN;  // nodes per wave
  const int t = threadIdx.x;
  const int lane = t & 63;
  const int wave = t >> 6;
  const int f4  = (lane % LPN) * 4;
  const int sub = lane / LPN;
  const int node = (blockIdx.x * 4 + wave) * NPW + sub;
  const int start = row_start[node];
  const int end   = row_start[node + 1];
  float ax = 0.0f, ay = 0.0f, az = 0.0f, aw = 0.0f;
  int i = start;
  for (; i + 4 <= end; i += 4) {
    int s0 = csr_src[i + 0];
    int s1 = csr_src[i + 1];
    int s2 = csr_src[i + 2];
    int s3 = csr_src[i + 3];
    float4 v0 = *reinterpret_cast<const float4*>(&hw[(size_t)s0 * D + f4]);
    float4 v1 = *reinterpret_cast<const float4*>(&hw[(size_t)s1 * D + f4]);
    float4 v2 = *reinterpret_cast<const float4*>(&hw[(size_t)s2 * D + f4]);
    float4 v3 = *reinterpret_cast<const float4*>(&hw[(size_t)s3 * D + f4]);
    ax += v0.x + v1.x + v2.x + v3.x;
    ay += v0.y + v1.y + v2.y + v3.y;
    az += v0.z + v1.z + v2.z + v3.z;
    aw += v0.w + v1.w + v2.w + v3.w;
  }
  for (; i < end; ++i) {
    float4 v = *reinterpret_cast<const float4*>(&hw[(size_t)csr_src[i] * D + f4]);
    ax += v.x; ay += v.y; az += v.z; aw += v.w;
  }
  float nrm = dst_norm[node];
  float4 b4 = *reinterpret_cast<const float4*>(&bias[f4]);
  float4 r;
  r.x = fmaxf(ax * nrm + b4.x, 0.0f);
  r.y = fmaxf(ay * nrm + b4.y, 0.0f);
  r.z = fmaxf(az * nrm + b4.z, 0.0f);
  r.w = fmaxf(aw * nrm + b4.w, 0.0f);
  *reinterpret_cast<float4*>(&out[(size_t)node * D + f4]) = r;
}

// ---------------- pooling ----------------
__global__ __launch_bounds__(256) void k_pool(const float* __restrict__ h3,
                                              const int* __restrict__ gid,
                                              float* __restrict__ sums,
                                              float* __restrict__ cnt) {
  const int t = threadIdx.x;
  const int f = t & 15;
  const int grp = t >> 4;
  const int base = blockIdx.x * POOL_NPB;
  float acc = 0.0f, c = 0.0f;
  int cur = gid[base + grp];
#pragma unroll 4
  for (int k = 0; k < POOL_NPB / 16; ++k) {
    int node = base + grp + k * 16;
    int g = gid[node];
    float v = h3[(size_t)node * 16 + f];
    if (g != cur) {
      atomicAdd(&sums[cur * 16 + f], acc);
      if (f == 0) atomicAdd(&cnt[cur], c);
      acc = 0.0f; c = 0.0f; cur = g;
    }
    acc += v; c += 1.0f;
  }
  atomicAdd(&sums[cur * 16 + f], acc);
  if (f == 0) atomicAdd(&cnt[cur], c);
}

__global__ __launch_bounds__(128) void k_classify(const float* __restrict__ sums,
                                                  const float* __restrict__ cnt,
                                                  const float* __restrict__ Wc,
                                                  const float* __restrict__ bc,
                                                  float* __restrict__ out) {
  int g = threadIdx.x;
  float c = cnt[g]; if (c < 1.0f) c = 1.0f;
  float acc = 0.0f;
#pragma unroll
  for (int f = 0; f < 16; ++f) acc += (sums[g * 16 + f] / c) * Wc[f];
  out[g] = acc + bc[0];
}

// ---------------- launch ----------------
extern "C" void kernel_launch(void* const* d_in, const int* in_sizes, int n_in,
                              void* d_out, int out_size, void* d_ws, size_t ws_size,
                              hipStream_t stream) {
  const float* features = (const float*)d_in[0];
  const int*   src      = (const int*)d_in[1];
  const int*   dst      = (const int*)d_in[2];
  const int*   gid      = (const int*)d_in[3];
  const float* W0 = (const float*)d_in[4];
  const float* b0 = (const float*)d_in[5];
  const float* W1 = (const float*)d_in[6];
  const float* b1 = (const float*)d_in[7];
  const float* W2 = (const float*)d_in[8];
  const float* b2 = (const float*)d_in[9];
  const float* Wc = (const float*)d_in[10];
  const float* bc = (const float*)d_in[11];
  float* out = (float*)d_out;

  char* w = (char*)d_ws;
  auto alloc = [&](size_t bytes) {
    void* p = (void*)w;
    w += (bytes + 255) & ~(size_t)255;
    return p;
  };
  float* src_norm    = (float*)alloc((size_t)N_NODES * 4);
  float* dst_norm    = (float*)alloc((size_t)N_NODES * 4);
  int*   row_start   = (int*)alloc((size_t)(N_NODES + 1) * 4);
  int*   cursor_d    = (int*)alloc(NB * 4);
  int*   cursor_s    = (int*)alloc(NB * 4);
  int*   bucket_base = (int*)alloc(NB * 4);
  int*   csr_src     = (int*)alloc((size_t)N_EDGES * 4);
  float* buf0        = (float*)alloc((size_t)N_NODES * 64 * 4);
  float* buf1        = (float*)alloc((size_t)N_NODES * 64 * 4);
  float* sums        = (float*)alloc((size_t)N_GRAPHS * 16 * 4);
  float* cnt         = (float*)alloc((size_t)N_GRAPHS * 4);
  unsigned int*   recs_d = (unsigned int*)buf0;
  unsigned short* recs_s = (unsigned short*)buf1;

  hipMemsetAsync(sums, 0, (size_t)(N_GRAPHS * 16 + N_GRAPHS) * 4, stream);

  k_init_buckets<<<1, 256, 0, stream>>>(cursor_d, cursor_s);
  k_bin<<<N_EDGES / (256 * BIN_EPT), 256, 0, stream>>>(src, dst, cursor_d, cursor_s,
                                                       recs_d, recs_s);
  k_outdeg<<<NB, 512, 0, stream>>>(recs_s, cursor_s, src_norm);
  k_bucket_scan<<<1, 256, 0, stream>>>(cursor_d, bucket_base, row_start);
  k_fill2<<<NB, 512, 0, stream>>>(recs_d, cursor_d, bucket_base, row_start,
                                  dst_norm, csr_src);

  // layer 0: 256 -> 64
  k_gemm<256, 64, 8, 128><<<N_NODES / 128, 128, 0, stream>>>(features, src_norm, W0, buf0);
  k_agg<64><<<N_NODES / 16, 256, 0, stream>>>(buf0, row_start, csr_src, dst_norm, b0, buf1);
  // layer 1: 64 -> 32
  k_gemm<64, 32, 8, 64><<<N_NODES / 128, 64, 0, stream>>>(buf1, src_norm, W1, buf0);
  k_agg<32><<<N_NODES / 32, 256, 0, stream>>>(buf0, row_start, csr_src, dst_norm, b1, buf1);
  // layer 2: 32 -> 16
  k_gemm<32, 16, 4, 64><<<N_NODES / 128, 64, 0, stream>>>(buf1, src_norm, W2, buf0);
  k_agg<16><<<N_NODES / 64, 256, 0, stream>>>(buf0, row_start, csr_src, dst_norm, b2, buf1);

  k_pool<<<N_NODES / POOL_NPB, 256, 0, stream>>>(buf1, gid, sums, cnt);
  k_classify<<<1, 128, 0, stream>>>(sums, cnt, Wc, bc, out);
}

// Round 13
// 339.228 us; speedup vs baseline: 1.1640x; 1.1640x over previous
//
#include <hip/hip_runtime.h>

#define N_NODES 131072
#define N_EDGES 2097152
#define N_GRAPHS 128
#define POOL_NPB 256       // nodes per block in k_pool
#define NB 256             // buckets (both src- and dst-binning)
#define BUCKET_SHIFT 9     // 512 nodes per bucket
#define BUCKET_CAP 9728    // max edges per bucket (mean 8192, +17 sigma)
#define BIN_EPT 32         // edges per thread per pass in k_bin (8192/block)

// ---------------- bucket cursor init ----------------
__global__ __launch_bounds__(256) void k_init_buckets(int* __restrict__ cursor_d,
                                                      int* __restrict__ cursor_s) {
  int i = threadIdx.x;
  cursor_d[i] = i * BUCKET_CAP;
  cursor_s[i] = i * BUCKET_CAP;
}

// ---------------- phase A: bin edges (two-pass, zero per-edge global atomics) ----
__global__ __launch_bounds__(256) void k_bin(const int* __restrict__ src,
                                             const int* __restrict__ dst,
                                             int* __restrict__ cursor_d,
                                             int* __restrict__ cursor_s,
                                             unsigned int* __restrict__ recs_d,
                                             unsigned short* __restrict__ recs_s) {
  __shared__ int hd[NB];
  __shared__ int hs[NB];
  const int t = threadIdx.x;
  const int e0 = blockIdx.x * (256 * BIN_EPT);
  hd[t] = 0; hs[t] = 0;
  __syncthreads();
#pragma unroll 4
  for (int k = 0; k < BIN_EPT; ++k) {
    int e = e0 + k * 256 + t;
    atomicAdd(&hd[dst[e] >> BUCKET_SHIFT], 1);
    atomicAdd(&hs[src[e] >> BUCKET_SHIFT], 1);
  }
  __syncthreads();
  { int c = hd[t]; hd[t] = c ? atomicAdd(&cursor_d[t], c) : 0; }
  { int c = hs[t]; hs[t] = c ? atomicAdd(&cursor_s[t], c) : 0; }
  __syncthreads();
#pragma unroll 4
  for (int k = 0; k < BIN_EPT; ++k) {
    int e = e0 + k * 256 + t;      // re-read (L2/L3 hot)
    int s = src[e];
    int d = dst[e];
    int pd = atomicAdd(&hd[d >> BUCKET_SHIFT], 1);
    recs_d[pd] = ((unsigned int)s << BUCKET_SHIFT) | (unsigned int)(d & 511);
    int ps = atomicAdd(&hs[s >> BUCKET_SHIFT], 1);
    recs_s[ps] = (unsigned short)(s & 511);
  }
}

// ---------------- outdeg via LDS histogram -> src_norm ----------------
__global__ __launch_bounds__(512) void k_outdeg(const unsigned short* __restrict__ recs_s,
                                                const int* __restrict__ cursor_s,
                                                float* __restrict__ src_norm) {
  __shared__ int hist[512];
  const int b = blockIdx.x;
  const int t = threadIdx.x;
  hist[t] = 0;
  __syncthreads();
  const int beg = b * BUCKET_CAP;
  const int end = cursor_s[b];
  for (int i = beg + t; i < end; i += 512) atomicAdd(&hist[recs_s[i]], 1);
  __syncthreads();
  int od = hist[t]; if (od < 1) od = 1;
  src_norm[b * 512 + t] = 1.0f / sqrtf((float)od);
}

// ---------------- bucket base: exclusive scan of dst-bucket counts ----------------
__global__ __launch_bounds__(256) void k_bucket_scan(const int* __restrict__ cursor_d,
                                                     int* __restrict__ bucket_base,
                                                     int* __restrict__ row_start) {
  __shared__ int tmp[256];
  int t = threadIdx.x;
  int c = cursor_d[t] - t * BUCKET_CAP;
  tmp[t] = c;
  __syncthreads();
  for (int off = 1; off < 256; off <<= 1) {
    int x = (t >= off) ? tmp[t - off] : 0;
    __syncthreads();
    tmp[t] += x;
    __syncthreads();
  }
  bucket_base[t] = tmp[t] - c;
  if (t == 0) row_start[N_NODES] = N_EDGES;
}

// ---------------- phase B: indeg+row_start+dst_norm+CSR fill, all in LDS --------
__global__ __launch_bounds__(512) void k_fill2(const unsigned int* __restrict__ recs_d,
                                               const int* __restrict__ cursor_d,
                                               const int* __restrict__ bucket_base,
                                               int* __restrict__ row_start,
                                               float* __restrict__ dst_norm,
                                               int* __restrict__ csr_src) {
  __shared__ int hist[512];
  __shared__ int lcur[512];
  const int b = blockIdx.x;
  const int t = threadIdx.x;
  hist[t] = 0;
  __syncthreads();
  const int beg = b * BUCKET_CAP;
  const int end = cursor_d[b];
  for (int i = beg + t; i < end; i += 512) atomicAdd(&hist[recs_d[i] & 511], 1);
  __syncthreads();
  int deg = hist[t];
  lcur[t] = deg;
  __syncthreads();
  for (int off = 1; off < 512; off <<= 1) {
    int x = (t >= off) ? lcur[t - off] : 0;
    __syncthreads();
    lcur[t] += x;
    __syncthreads();
  }
  int rs = bucket_base[b] + lcur[t] - deg;
  row_start[b * 512 + t] = rs;
  int dd = deg < 1 ? 1 : deg;
  dst_norm[b * 512 + t] = 1.0f / sqrtf((float)dd);
  lcur[t] = rs;
  __syncthreads();
  for (int i = beg + t; i < end; i += 512) {
    unsigned int r = recs_d[i];
    int p = atomicAdd(&lcur[r & 511], 1);
    csr_src[p] = (int)(r >> BUCKET_SHIFT);
  }
}

// ---------------- GEMM v7: lane=row, B via wave-uniform SGPR loads --------------
// 256 threads = 4 waves; wave wv owns cols [wv*CPW, (wv+1)*CPW), lane = row.
// Per kk each lane issues ONE ds_read_b32 (stride-1 permuted: conflict-free)
// and CPW FMAs with B operands from s_load (wave-uniform address via
// readfirstlane -> scalar pipe, zero LDS/VMEM vector traffic for B).
// r11 (4x4 tile) sat at its LDS-issue floor (~2 b128 / 16 FMA = 79us); this
// config's LDS cost (1 b32/16 FMA) sits below the 27us VALU floor.
// acc[CPW]+addr ~ 40 VGPR, LDS 8KB -> 8 blocks/CU (grid 2048) = 32 waves/CU.
template <int DIN, int DOUT>
__global__ __launch_bounds__(256) void k_gemm(const float* __restrict__ h,
                                              const float* __restrict__ src_norm,
                                              const float* __restrict__ W,
                                              float* __restrict__ out) {
  constexpr int KC   = 32;
  constexpr int ROWS = 64;
  constexpr int NCH  = DIN / KC;
  constexpr int CPW  = DOUT / 4;     // cols per wave
  __shared__ float hT[KC][ROWS];

  const int t    = threadIdx.x;
  const int lane = t & 63;
  const int wv   = __builtin_amdgcn_readfirstlane(t >> 6);
  const int rowBase = blockIdx.x * ROWS;
  const int rg0 = t >> 3;          // 0..31
  const int ks  = (t & 7) * 4;     // 0..28

  float acc[CPW];
#pragma unroll
  for (int j = 0; j < CPW; ++j) acc[j] = 0.0f;

  for (int ch = 0; ch < NCH; ++ch) {
    const int kc = ch * KC;
    // stage hT (transposed, swizzled writes) -- r11's proven pattern
#pragma unroll
    for (int p = 0; p < 2; ++p) {
      int rg = rg0 + 32 * p;
      float4 v = *reinterpret_cast<const float4*>(&h[(size_t)(rowBase + rg) * DIN + kc + ks]);
      hT[ks + 0][rg ^ ((((ks + 0) >> 3) & 3) << 3)] = v.x;
      hT[ks + 1][rg ^ ((((ks + 1) >> 3) & 3) << 3)] = v.y;
      hT[ks + 2][rg ^ ((((ks + 2) >> 3) & 3) << 3)] = v.z;
      hT[ks + 3][rg ^ ((((ks + 3) >> 3) & 3) << 3)] = v.w;
    }
    __syncthreads();
    const float* Wrow = &W[(size_t)kc * DOUT + wv * CPW];  // wave-uniform base
#pragma unroll
    for (int kk = 0; kk < KC; ++kk) {
      const int swz = ((kk >> 3) & 3) << 3;
      float a = hT[kk][lane ^ swz];
#pragma unroll
      for (int j = 0; j < CPW; ++j)
        acc[j] += a * Wrow[kk * DOUT + j];   // uniform addr -> s_load
    }
    __syncthreads();
  }

  const int row = rowBase + lane;
  float nrm = src_norm[row];
  float* op = &out[(size_t)row * DOUT + wv * CPW];
#pragma unroll
  for (int q = 0; q < CPW / 4; ++q) {
    float4 v = {acc[q * 4 + 0] * nrm, acc[q * 4 + 1] * nrm,
                acc[q * 4 + 2] * nrm, acc[q * 4 + 3] * nrm};
    *reinterpret_cast<float4*>(op + q * 4) = v;
  }
}

// ---------------- aggregation: float4 gathers, D/4 lanes per node ----------------
template <int D>
__global__ __launch_bounds__(256) void k_agg(const float* __restrict__ hw,
                                             const int* __restrict__ row_start,
                                             const int* __restrict__ csr_src,
                                             const float* __restrict__ dst_norm,
                                             const float* __restrict__ bias,
                                             float* __restrict__ out) {
  constexpr int LPN = D / 4;     // lanes per node
  constexpr int NPW = 64 / LPN;  // nodes per wave
  const int t = threadIdx.x;
  const int lane = t & 63;
  const int wave = t >> 6;
  const int f4  = (lane % LPN) * 4;
  const int sub = lane / LPN;
  const int node = (blockIdx.x * 4 + wave) * NPW + sub;
  const int start = row_start[node];
  const int end   = row_start[node + 1];
  float ax = 0.0f, ay = 0.0f, az = 0.0f, aw = 0.0f;
  int i = start;
  for (; i + 4 <= end; i += 4) {
    int s0 = csr_src[i + 0];
    int s1 = csr_src[i + 1];
    int s2 = csr_src[i + 2];
    int s3 = csr_src[i + 3];
    float4 v0 = *reinterpret_cast<const float4*>(&hw[(size_t)s0 * D + f4]);
    float4 v1 = *reinterpret_cast<const float4*>(&hw[(size_t)s1 * D + f4]);
    float4 v2 = *reinterpret_cast<const float4*>(&hw[(size_t)s2 * D + f4]);
    float4 v3 = *reinterpret_cast<const float4*>(&hw[(size_t)s3 * D + f4]);
    ax += v0.x + v1.x + v2.x + v3.x;
    ay += v0.y + v1.y + v2.y + v3.y;
    az += v0.z + v1.z + v2.z + v3.z;
    aw += v0.w + v1.w + v2.w + v3.w;
  }
  for (; i < end; ++i) {
    float4 v = *reinterpret_cast<const float4*>(&hw[(size_t)csr_src[i] * D + f4]);
    ax += v.x; ay += v.y; az += v.z; aw += v.w;
  }
  float nrm = dst_norm[node];
  float4 b4 = *reinterpret_cast<const float4*>(&bias[f4]);
  float4 r;
  r.x = fmaxf(ax * nrm + b4.x, 0.0f);
  r.y = fmaxf(ay * nrm + b4.y, 0.0f);
  r.z = fmaxf(az * nrm + b4.z, 0.0f);
  r.w = fmaxf(aw * nrm + b4.w, 0.0f);
  *reinterpret_cast<float4*>(&out[(size_t)node * D + f4]) = r;
}

// ---------------- pooling ----------------
__global__ __launch_bounds__(256) void k_pool(const float* __restrict__ h3,
                                              const int* __restrict__ gid,
                                              float* __restrict__ sums,
                                              float* __restrict__ cnt) {
  const int t = threadIdx.x;
  const int f = t & 15;
  const int grp = t >> 4;
  const int base = blockIdx.x * POOL_NPB;
  float acc = 0.0f, c = 0.0f;
  int cur = gid[base + grp];
#pragma unroll 4
  for (int k = 0; k < POOL_NPB / 16; ++k) {
    int node = base + grp + k * 16;
    int g = gid[node];
    float v = h3[(size_t)node * 16 + f];
    if (g != cur) {
      atomicAdd(&sums[cur * 16 + f], acc);
      if (f == 0) atomicAdd(&cnt[cur], c);
      acc = 0.0f; c = 0.0f; cur = g;
    }
    acc += v; c += 1.0f;
  }
  atomicAdd(&sums[cur * 16 + f], acc);
  if (f == 0) atomicAdd(&cnt[cur], c);
}

__global__ __launch_bounds__(128) void k_classify(const float* __restrict__ sums,
                                                  const float* __restrict__ cnt,
                                                  const float* __restrict__ Wc,
                                                  const float* __restrict__ bc,
                                                  float* __restrict__ out) {
  int g = threadIdx.x;
  float c = cnt[g]; if (c < 1.0f) c = 1.0f;
  float acc = 0.0f;
#pragma unroll
  for (int f = 0; f < 16; ++f) acc += (sums[g * 16 + f] / c) * Wc[f];
  out[g] = acc + bc[0];
}

// ---------------- launch ----------------
extern "C" void kernel_launch(void* const* d_in, const int* in_sizes, int n_in,
                              void* d_out, int out_size, void* d_ws, size_t ws_size,
                              hipStream_t stream) {
  const float* features = (const float*)d_in[0];
  const int*   src      = (const int*)d_in[1];
  const int*   dst      = (const int*)d_in[2];
  const int*   gid      = (const int*)d_in[3];
  const float* W0 = (const float*)d_in[4];
  const float* b0 = (const float*)d_in[5];
  const float* W1 = (const float*)d_in[6];
  const float* b1 = (const float*)d_in[7];
  const float* W2 = (const float*)d_in[8];
  const float* b2 = (const float*)d_in[9];
  const float* Wc = (const float*)d_in[10];
  const float* bc = (const float*)d_in[11];
  float* out = (float*)d_out;

  char* w = (char*)d_ws;
  auto alloc = [&](size_t bytes) {
    void* p = (void*)w;
    w += (bytes + 255) & ~(size_t)255;
    return p;
  };
  float* src_norm    = (float*)alloc((size_t)N_NODES * 4);
  float* dst_norm    = (float*)alloc((size_t)N_NODES * 4);
  int*   row_start   = (int*)alloc((size_t)(N_NODES + 1) * 4);
  int*   cursor_d    = (int*)alloc(NB * 4);
  int*   cursor_s    = (int*)alloc(NB * 4);
  int*   bucket_base = (int*)alloc(NB * 4);
  int*   csr_src     = (int*)alloc((size_t)N_EDGES * 4);
  float* buf0        = (float*)alloc((size_t)N_NODES * 64 * 4);
  float* buf1        = (float*)alloc((size_t)N_NODES * 64 * 4);
  float* sums        = (float*)alloc((size_t)N_GRAPHS * 16 * 4);
  float* cnt         = (float*)alloc((size_t)N_GRAPHS * 4);
  unsigned int*   recs_d = (unsigned int*)buf0;
  unsigned short* recs_s = (unsigned short*)buf1;

  hipMemsetAsync(sums, 0, (size_t)(N_GRAPHS * 16 + N_GRAPHS) * 4, stream);

  k_init_buckets<<<1, 256, 0, stream>>>(cursor_d, cursor_s);
  k_bin<<<N_EDGES / (256 * BIN_EPT), 256, 0, stream>>>(src, dst, cursor_d, cursor_s,
                                                       recs_d, recs_s);
  k_outdeg<<<NB, 512, 0, stream>>>(recs_s, cursor_s, src_norm);
  k_bucket_scan<<<1, 256, 0, stream>>>(cursor_d, bucket_base, row_start);
  k_fill2<<<NB, 512, 0, stream>>>(recs_d, cursor_d, bucket_base, row_start,
                                  dst_norm, csr_src);

  // layer 0: 256 -> 64
  k_gemm<256, 64><<<N_NODES / 64, 256, 0, stream>>>(features, src_norm, W0, buf0);
  k_agg<64><<<N_NODES / 16, 256, 0, stream>>>(buf0, row_start, csr_src, dst_norm, b0, buf1);
  // layer 1: 64 -> 32
  k_gemm<64, 32><<<N_NODES / 64, 256, 0, stream>>>(buf1, src_norm, W1, buf0);
  k_agg<32><<<N_NODES / 32, 256, 0, stream>>>(buf0, row_start, csr_src, dst_norm, b1, buf1);
  // layer 2: 32 -> 16
  k_gemm<32, 16><<<N_NODES / 64, 256, 0, stream>>>(buf1, src_norm, W2, buf0);
  k_agg<16><<<N_NODES / 64, 256, 0, stream>>>(buf0, row_start, csr_src, dst_norm, b2, buf1);

  k_pool<<<N_NODES / POOL_NPB, 256, 0, stream>>>(buf1, gid, sums, cnt);
  k_classify<<<1, 128, 0, stream>>>(sums, cnt, Wc, bc, out);
}

// Round 14
// 337.418 us; speedup vs baseline: 1.1702x; 1.0054x over previous
//
#include <hip/hip_runtime.h>

#define N_NODES 131072
#define N_EDGES 2097152
#define N_GRAPHS 128
#define POOL_NPB 256       // nodes per block in k_pool
#define NB 256             // buckets (both src- and dst-binning)
#define BUCKET_SHIFT 9     // 512 nodes per bucket
#define BUCKET_CAP 9728    // max edges per bucket (mean 8192, +17 sigma)
#define BIN_EPT 32         // edges per thread per pass in k_bin (8192/block)

// ---------------- bucket cursor init ----------------
__global__ __launch_bounds__(256) void k_init_buckets(int* __restrict__ cursor_d,
                                                      int* __restrict__ cursor_s) {
  int i = threadIdx.x;
  cursor_d[i] = i * BUCKET_CAP;
  cursor_s[i] = i * BUCKET_CAP;
}

// ---------------- phase A: bin edges (two-pass, zero per-edge global atomics) ----
__global__ __launch_bounds__(256) void k_bin(const int* __restrict__ src,
                                             const int* __restrict__ dst,
                                             int* __restrict__ cursor_d,
                                             int* __restrict__ cursor_s,
                                             unsigned int* __restrict__ recs_d,
                                             unsigned short* __restrict__ recs_s) {
  __shared__ int hd[NB];
  __shared__ int hs[NB];
  const int t = threadIdx.x;
  const int e0 = blockIdx.x * (256 * BIN_EPT);
  hd[t] = 0; hs[t] = 0;
  __syncthreads();
#pragma unroll 4
  for (int k = 0; k < BIN_EPT; ++k) {
    int e = e0 + k * 256 + t;
    atomicAdd(&hd[dst[e] >> BUCKET_SHIFT], 1);
    atomicAdd(&hs[src[e] >> BUCKET_SHIFT], 1);
  }
  __syncthreads();
  { int c = hd[t]; hd[t] = c ? atomicAdd(&cursor_d[t], c) : 0; }
  { int c = hs[t]; hs[t] = c ? atomicAdd(&cursor_s[t], c) : 0; }
  __syncthreads();
#pragma unroll 4
  for (int k = 0; k < BIN_EPT; ++k) {
    int e = e0 + k * 256 + t;      // re-read (L2/L3 hot)
    int s = src[e];
    int d = dst[e];
    int pd = atomicAdd(&hd[d >> BUCKET_SHIFT], 1);
    recs_d[pd] = ((unsigned int)s << BUCKET_SHIFT) | (unsigned int)(d & 511);
    int ps = atomicAdd(&hs[s >> BUCKET_SHIFT], 1);
    recs_s[ps] = (unsigned short)(s & 511);
  }
}

// ---------------- outdeg via LDS histogram -> src_norm ----------------
__global__ __launch_bounds__(512) void k_outdeg(const unsigned short* __restrict__ recs_s,
                                                const int* __restrict__ cursor_s,
                                                float* __restrict__ src_norm) {
  __shared__ int hist[512];
  const int b = blockIdx.x;
  const int t = threadIdx.x;
  hist[t] = 0;
  __syncthreads();
  const int beg = b * BUCKET_CAP;
  const int end = cursor_s[b];
  for (int i = beg + t; i < end; i += 512) atomicAdd(&hist[recs_s[i]], 1);
  __syncthreads();
  int od = hist[t]; if (od < 1) od = 1;
  src_norm[b * 512 + t] = 1.0f / sqrtf((float)od);
}

// ---------------- bucket base: exclusive scan of dst-bucket counts ----------------
__global__ __launch_bounds__(256) void k_bucket_scan(const int* __restrict__ cursor_d,
                                                     int* __restrict__ bucket_base,
                                                     int* __restrict__ row_start) {
  __shared__ int tmp[256];
  int t = threadIdx.x;
  int c = cursor_d[t] - t * BUCKET_CAP;
  tmp[t] = c;
  __syncthreads();
  for (int off = 1; off < 256; off <<= 1) {
    int x = (t >= off) ? tmp[t - off] : 0;
    __syncthreads();
    tmp[t] += x;
    __syncthreads();
  }
  bucket_base[t] = tmp[t] - c;
  if (t == 0) row_start[N_NODES] = N_EDGES;
}

// ---------------- phase B: indeg+row_start+dst_norm+CSR fill, all in LDS --------
__global__ __launch_bounds__(512) void k_fill2(const unsigned int* __restrict__ recs_d,
                                               const int* __restrict__ cursor_d,
                                               const int* __restrict__ bucket_base,
                                               int* __restrict__ row_start,
                                               float* __restrict__ dst_norm,
                                               int* __restrict__ csr_src) {
  __shared__ int hist[512];
  __shared__ int lcur[512];
  const int b = blockIdx.x;
  const int t = threadIdx.x;
  hist[t] = 0;
  __syncthreads();
  const int beg = b * BUCKET_CAP;
  const int end = cursor_d[b];
  for (int i = beg + t; i < end; i += 512) atomicAdd(&hist[recs_d[i] & 511], 1);
  __syncthreads();
  int deg = hist[t];
  lcur[t] = deg;
  __syncthreads();
  for (int off = 1; off < 512; off <<= 1) {
    int x = (t >= off) ? lcur[t - off] : 0;
    __syncthreads();
    lcur[t] += x;
    __syncthreads();
  }
  int rs = bucket_base[b] + lcur[t] - deg;
  row_start[b * 512 + t] = rs;
  int dd = deg < 1 ? 1 : deg;
  dst_norm[b * 512 + t] = 1.0f / sqrtf((float)dd);
  lcur[t] = rs;
  __syncthreads();
  for (int i = beg + t; i < end; i += 512) {
    unsigned int r = recs_d[i];
    int p = atomicAdd(&lcur[r & 511], 1);
    csr_src[p] = (int)(r >> BUCKET_SHIFT);
  }
}

// ---------------- GEMM v5 (r11, proven 79us for DIN=256): 64-row tile ----------
// ROWS=64, KC=32, LDS 16KB, VGPR 36 -> 8+ blocks/CU; staging latency hidden by
// TLP. XOR swizzle ((kk>>3)&3)<<3 keeps staging writes and A-reads
// conflict-free. Norm applied in epilogue (staging = pure copy).
template <int DIN, int DOUT>
__global__ __launch_bounds__(256) void k_gemm_v5(const float* __restrict__ h,
                                                 const float* __restrict__ src_norm,
                                                 const float* __restrict__ W,
                                                 float* __restrict__ out) {
  constexpr int KC   = 32;
  constexpr int ROWS = 64;
  constexpr int TN   = DOUT / 16;
  constexpr int WEL  = KC * DOUT;
  __shared__ float hT[KC][ROWS];
  __shared__ float Ws[KC][DOUT];

  const int t  = threadIdx.x;
  const int rowBase = blockIdx.x * ROWS;
  const int tr = t & 15;
  const int tc = t >> 4;
  const int rg0 = (t >> 3) & 31;
  const int ks  = (t & 7) * 4;

  float acc[4][TN];
#pragma unroll
  for (int i = 0; i < 4; ++i)
#pragma unroll
    for (int j = 0; j < TN; ++j) acc[i][j] = 0.0f;

  for (int kc = 0; kc < DIN; kc += KC) {
#pragma unroll
    for (int p = 0; p < 2; ++p) {
      int rg = rg0 + 32 * p;
      float4 v = *reinterpret_cast<const float4*>(&h[(size_t)(rowBase + rg) * DIN + kc + ks]);
      hT[ks + 0][rg ^ ((((ks + 0) >> 3) & 3) << 3)] = v.x;
      hT[ks + 1][rg ^ ((((ks + 1) >> 3) & 3) << 3)] = v.y;
      hT[ks + 2][rg ^ ((((ks + 2) >> 3) & 3) << 3)] = v.z;
      hT[ks + 3][rg ^ ((((ks + 3) >> 3) & 3) << 3)] = v.w;
    }
#pragma unroll
    for (int base = 0; base < WEL; base += 256 * 4) {
      int idx = base + t * 4;
      if (idx < WEL)
        *reinterpret_cast<float4*>(&Ws[0][0] + idx) =
            *reinterpret_cast<const float4*>(&W[(size_t)kc * DOUT + idx]);
    }
    __syncthreads();
#pragma unroll
    for (int kk = 0; kk < KC; ++kk) {
      const int swz = ((kk >> 3) & 3) << 3;
      float4 a0 = *reinterpret_cast<const float4*>(&hT[kk][(tr * 4) ^ swz]);
      float bb[TN];
#pragma unroll
      for (int j = 0; j < TN; ++j) bb[j] = Ws[kk][tc * TN + j];
      float av[4] = {a0.x, a0.y, a0.z, a0.w};
#pragma unroll
      for (int i = 0; i < 4; ++i)
#pragma unroll
        for (int j = 0; j < TN; ++j) acc[i][j] += av[i] * bb[j];
    }
    __syncthreads();
  }

#pragma unroll
  for (int i = 0; i < 4; ++i) {
    int row = rowBase + tr * 4 + i;
    float nrm = src_norm[row];
    float* op = &out[(size_t)row * DOUT + tc * TN];
    if constexpr (TN == 4) {
      float4 v = {acc[i][0] * nrm, acc[i][1] * nrm, acc[i][2] * nrm, acc[i][3] * nrm};
      *reinterpret_cast<float4*>(op) = v;
    } else if constexpr (TN == 2) {
      float2 v = {acc[i][0] * nrm, acc[i][1] * nrm};
      *reinterpret_cast<float2*>(op) = v;
    } else {
      op[0] = acc[i][0] * nrm;
    }
  }
}

// ---------------- GEMM v7 (r13, best for small DIN): lane=row, SGPR B ----------
template <int DIN, int DOUT>
__global__ __launch_bounds__(256) void k_gemm_v7(const float* __restrict__ h,
                                                 const float* __restrict__ src_norm,
                                                 const float* __restrict__ W,
                                                 float* __restrict__ out) {
  constexpr int KC   = 32;
  constexpr int ROWS = 64;
  constexpr int NCH  = DIN / KC;
  constexpr int CPW  = DOUT / 4;     // cols per wave
  __shared__ float hT[KC][ROWS];

  const int t    = threadIdx.x;
  const int lane = t & 63;
  const int wv   = __builtin_amdgcn_readfirstlane(t >> 6);
  const int rowBase = blockIdx.x * ROWS;
  const int rg0 = t >> 3;
  const int ks  = (t & 7) * 4;

  float acc[CPW];
#pragma unroll
  for (int j = 0; j < CPW; ++j) acc[j] = 0.0f;

  for (int ch = 0; ch < NCH; ++ch) {
    const int kc = ch * KC;
#pragma unroll
    for (int p = 0; p < 2; ++p) {
      int rg = rg0 + 32 * p;
      float4 v = *reinterpret_cast<const float4*>(&h[(size_t)(rowBase + rg) * DIN + kc + ks]);
      hT[ks + 0][rg ^ ((((ks + 0) >> 3) & 3) << 3)] = v.x;
      hT[ks + 1][rg ^ ((((ks + 1) >> 3) & 3) << 3)] = v.y;
      hT[ks + 2][rg ^ ((((ks + 2) >> 3) & 3) << 3)] = v.z;
      hT[ks + 3][rg ^ ((((ks + 3) >> 3) & 3) << 3)] = v.w;
    }
    __syncthreads();
    const float* Wrow = &W[(size_t)kc * DOUT + wv * CPW];  // wave-uniform base
#pragma unroll
    for (int kk = 0; kk < KC; ++kk) {
      const int swz = ((kk >> 3) & 3) << 3;
      float a = hT[kk][lane ^ swz];
#pragma unroll
      for (int j = 0; j < CPW; ++j)
        acc[j] += a * Wrow[kk * DOUT + j];   // uniform addr -> s_load
    }
    __syncthreads();
  }

  const int row = rowBase + lane;
  float nrm = src_norm[row];
  float* op = &out[(size_t)row * DOUT + wv * CPW];
#pragma unroll
  for (int q = 0; q < CPW / 4; ++q) {
    float4 v = {acc[q * 4 + 0] * nrm, acc[q * 4 + 1] * nrm,
                acc[q * 4 + 2] * nrm, acc[q * 4 + 3] * nrm};
    *reinterpret_cast<float4*>(op + q * 4) = v;
  }
}

// ---------------- aggregation: float4 gathers, D/4 lanes per node ----------------
template <int D>
__global__ __launch_bounds__(256) void k_agg(const float* __restrict__ hw,
                                             const int* __restrict__ row_start,
                                             const int* __restrict__ csr_src,
                                             const float* __restrict__ dst_norm,
                                             const float* __restrict__ bias,
                                             float* __restrict__ out) {
  constexpr int LPN = D / 4;     // lanes per node
  constexpr int NPW = 64 / LPN;  // nodes per wave
  const int t = threadIdx.x;
  const int lane = t & 63;
  const int wave = t >> 6;
  const int f4  = (lane % LPN) * 4;
  const int sub = lane / LPN;
  const int node = (blockIdx.x * 4 + wave) * NPW + sub;
  const int start = row_start[node];
  const int end   = row_start[node + 1];
  float ax = 0.0f, ay = 0.0f, az = 0.0f, aw = 0.0f;
  int i = start;
  for (; i + 4 <= end; i += 4) {
    int s0 = csr_src[i + 0];
    int s1 = csr_src[i + 1];
    int s2 = csr_src[i + 2];
    int s3 = csr_src[i + 3];
    float4 v0 = *reinterpret_cast<const float4*>(&hw[(size_t)s0 * D + f4]);
    float4 v1 = *reinterpret_cast<const float4*>(&hw[(size_t)s1 * D + f4]);
    float4 v2 = *reinterpret_cast<const float4*>(&hw[(size_t)s2 * D + f4]);
    float4 v3 = *reinterpret_cast<const float4*>(&hw[(size_t)s3 * D + f4]);
    ax += v0.x + v1.x + v2.x + v3.x;
    ay += v0.y + v1.y + v2.y + v3.y;
    az += v0.z + v1.z + v2.z + v3.z;
    aw += v0.w + v1.w + v2.w + v3.w;
  }
  for (; i < end; ++i) {
    float4 v = *reinterpret_cast<const float4*>(&hw[(size_t)csr_src[i] * D + f4]);
    ax += v.x; ay += v.y; az += v.z; aw += v.w;
  }
  float nrm = dst_norm[node];
  float4 b4 = *reinterpret_cast<const float4*>(&bias[f4]);
  float4 r;
  r.x = fmaxf(ax * nrm + b4.x, 0.0f);
  r.y = fmaxf(ay * nrm + b4.y, 0.0f);
  r.z = fmaxf(az * nrm + b4.z, 0.0f);
  r.w = fmaxf(aw * nrm + b4.w, 0.0f);
  *reinterpret_cast<float4*>(&out[(size_t)node * D + f4]) = r;
}

// ---------------- pooling ----------------
__global__ __launch_bounds__(256) void k_pool(const float* __restrict__ h3,
                                              const int* __restrict__ gid,
                                              float* __restrict__ sums,
                                              float* __restrict__ cnt) {
  const int t = threadIdx.x;
  const int f = t & 15;
  const int grp = t >> 4;
  const int base = blockIdx.x * POOL_NPB;
  float acc = 0.0f, c = 0.0f;
  int cur = gid[base + grp];
#pragma unroll 4
  for (int k = 0; k < POOL_NPB / 16; ++k) {
    int node = base + grp + k * 16;
    int g = gid[node];
    float v = h3[(size_t)node * 16 + f];
    if (g != cur) {
      atomicAdd(&sums[cur * 16 + f], acc);
      if (f == 0) atomicAdd(&cnt[cur], c);
      acc = 0.0f; c = 0.0f; cur = g;
    }
    acc += v; c += 1.0f;
  }
  atomicAdd(&sums[cur * 16 + f], acc);
  if (f == 0) atomicAdd(&cnt[cur], c);
}

__global__ __launch_bounds__(128) void k_classify(const float* __restrict__ sums,
                                                  const float* __restrict__ cnt,
                                                  const float* __restrict__ Wc,
                                                  const float* __restrict__ bc,
                                                  float* __restrict__ out) {
  int g = threadIdx.x;
  float c = cnt[g]; if (c < 1.0f) c = 1.0f;
  float acc = 0.0f;
#pragma unroll
  for (int f = 0; f < 16; ++f) acc += (sums[g * 16 + f] / c) * Wc[f];
  out[g] = acc + bc[0];
}

// ---------------- launch ----------------
extern "C" void kernel_launch(void* const* d_in, const int* in_sizes, int n_in,
                              void* d_out, int out_size, void* d_ws, size_t ws_size,
                              hipStream_t stream) {
  const float* features = (const float*)d_in[0];
  const int*   src      = (const int*)d_in[1];
  const int*   dst      = (const int*)d_in[2];
  const int*   gid      = (const int*)d_in[3];
  const float* W0 = (const float*)d_in[4];
  const float* b0 = (const float*)d_in[5];
  const float* W1 = (const float*)d_in[6];
  const float* b1 = (const float*)d_in[7];
  const float* W2 = (const float*)d_in[8];
  const float* b2 = (const float*)d_in[9];
  const float* Wc = (const float*)d_in[10];
  const float* bc = (const float*)d_in[11];
  float* out = (float*)d_out;

  char* w = (char*)d_ws;
  auto alloc = [&](size_t bytes) {
    void* p = (void*)w;
    w += (bytes + 255) & ~(size_t)255;
    return p;
  };
  float* src_norm    = (float*)alloc((size_t)N_NODES * 4);
  float* dst_norm    = (float*)alloc((size_t)N_NODES * 4);
  int*   row_start   = (int*)alloc((size_t)(N_NODES + 1) * 4);
  int*   cursor_d    = (int*)alloc(NB * 4);
  int*   cursor_s    = (int*)alloc(NB * 4);
  int*   bucket_base = (int*)alloc(NB * 4);
  int*   csr_src     = (int*)alloc((size_t)N_EDGES * 4);
  float* buf0        = (float*)alloc((size_t)N_NODES * 64 * 4);
  float* buf1        = (float*)alloc((size_t)N_NODES * 64 * 4);
  float* sums        = (float*)alloc((size_t)N_GRAPHS * 16 * 4);
  float* cnt         = (float*)alloc((size_t)N_GRAPHS * 4);
  unsigned int*   recs_d = (unsigned int*)buf0;
  unsigned short* recs_s = (unsigned short*)buf1;

  hipMemsetAsync(sums, 0, (size_t)(N_GRAPHS * 16 + N_GRAPHS) * 4, stream);

  k_init_buckets<<<1, 256, 0, stream>>>(cursor_d, cursor_s);
  k_bin<<<N_EDGES / (256 * BIN_EPT), 256, 0, stream>>>(src, dst, cursor_d, cursor_s,
                                                       recs_d, recs_s);
  k_outdeg<<<NB, 512, 0, stream>>>(recs_s, cursor_s, src_norm);
  k_bucket_scan<<<1, 256, 0, stream>>>(cursor_d, bucket_base, row_start);
  k_fill2<<<NB, 512, 0, stream>>>(recs_d, cursor_d, bucket_base, row_start,
                                  dst_norm, csr_src);

  // layer 0: 256 -> 64 (v5: proven best for large DIN)
  k_gemm_v5<256, 64><<<N_NODES / 64, 256, 0, stream>>>(features, src_norm, W0, buf0);
  k_agg<64><<<N_NODES / 16, 256, 0, stream>>>(buf0, row_start, csr_src, dst_norm, b0, buf1);
  // layer 1: 64 -> 32 (v7: proven best for small DIN)
  k_gemm_v7<64, 32><<<N_NODES / 64, 256, 0, stream>>>(buf1, src_norm, W1, buf0);
  k_agg<32><<<N_NODES / 32, 256, 0, stream>>>(buf0, row_start, csr_src, dst_norm, b1, buf1);
  // layer 2: 32 -> 16 (v7)
  k_gemm_v7<32, 16><<<N_NODES / 64, 256, 0, stream>>>(buf1, src_norm, W2, buf0);
  k_agg<16><<<N_NODES / 64, 256, 0, stream>>>(buf0, row_start, csr_src, dst_norm, b2, buf1);

  k_pool<<<N_NODES / POOL_NPB, 256, 0, stream>>>(buf1, gid, sums, cnt);
  k_classify<<<1, 128, 0, stream>>>(sums, cnt, Wc, bc, out);
}

// Round 15
// 334.440 us; speedup vs baseline: 1.1806x; 1.0089x over previous
//
#include <hip/hip_runtime.h>

#define N_NODES 131072
#define N_EDGES 2097152
#define N_GRAPHS 128
#define POOL_NPB 256       // nodes per block in k_pool
#define NB 256             // buckets (both src- and dst-binning)
#define BUCKET_SHIFT 9     // 512 nodes per bucket
#define BUCKET_CAP 9728    // max edges per bucket (mean 8192, +17 sigma)
#define BIN_EPT 32         // edges per thread per pass in k_bin (8192/block)

// ---------------- bucket cursor init ----------------
__global__ __launch_bounds__(256) void k_init_buckets(int* __restrict__ cursor_d,
                                                      int* __restrict__ cursor_s) {
  int i = threadIdx.x;
  cursor_d[i] = i * BUCKET_CAP;
  cursor_s[i] = i * BUCKET_CAP;
}

// ---------------- phase A: bin edges (two-pass, zero per-edge global atomics) ----
__global__ __launch_bounds__(256) void k_bin(const int* __restrict__ src,
                                             const int* __restrict__ dst,
                                             int* __restrict__ cursor_d,
                                             int* __restrict__ cursor_s,
                                             unsigned int* __restrict__ recs_d,
                                             unsigned short* __restrict__ recs_s) {
  __shared__ int hd[NB];
  __shared__ int hs[NB];
  const int t = threadIdx.x;
  const int e0 = blockIdx.x * (256 * BIN_EPT);
  hd[t] = 0; hs[t] = 0;
  __syncthreads();
#pragma unroll 4
  for (int k = 0; k < BIN_EPT; ++k) {
    int e = e0 + k * 256 + t;
    atomicAdd(&hd[dst[e] >> BUCKET_SHIFT], 1);
    atomicAdd(&hs[src[e] >> BUCKET_SHIFT], 1);
  }
  __syncthreads();
  { int c = hd[t]; hd[t] = c ? atomicAdd(&cursor_d[t], c) : 0; }
  { int c = hs[t]; hs[t] = c ? atomicAdd(&cursor_s[t], c) : 0; }
  __syncthreads();
#pragma unroll 4
  for (int k = 0; k < BIN_EPT; ++k) {
    int e = e0 + k * 256 + t;      // re-read (L2/L3 hot)
    int s = src[e];
    int d = dst[e];
    int pd = atomicAdd(&hd[d >> BUCKET_SHIFT], 1);
    recs_d[pd] = ((unsigned int)s << BUCKET_SHIFT) | (unsigned int)(d & 511);
    int ps = atomicAdd(&hs[s >> BUCKET_SHIFT], 1);
    recs_s[ps] = (unsigned short)(s & 511);
  }
}

// ---------------- outdeg via LDS histogram -> src_norm ----------------
__global__ __launch_bounds__(512) void k_outdeg(const unsigned short* __restrict__ recs_s,
                                                const int* __restrict__ cursor_s,
                                                float* __restrict__ src_norm) {
  __shared__ int hist[512];
  const int b = blockIdx.x;
  const int t = threadIdx.x;
  hist[t] = 0;
  __syncthreads();
  const int beg = b * BUCKET_CAP;
  const int end = cursor_s[b];
  for (int i = beg + t; i < end; i += 512) atomicAdd(&hist[recs_s[i]], 1);
  __syncthreads();
  int od = hist[t]; if (od < 1) od = 1;
  src_norm[b * 512 + t] = 1.0f / sqrtf((float)od);
}

// ---------------- bucket base: exclusive scan of dst-bucket counts ----------------
__global__ __launch_bounds__(256) void k_bucket_scan(const int* __restrict__ cursor_d,
                                                     int* __restrict__ bucket_base,
                                                     int* __restrict__ row_start) {
  __shared__ int tmp[256];
  int t = threadIdx.x;
  int c = cursor_d[t] - t * BUCKET_CAP;
  tmp[t] = c;
  __syncthreads();
  for (int off = 1; off < 256; off <<= 1) {
    int x = (t >= off) ? tmp[t - off] : 0;
    __syncthreads();
    tmp[t] += x;
    __syncthreads();
  }
  bucket_base[t] = tmp[t] - c;
  if (t == 0) row_start[N_NODES] = N_EDGES;
}

// ---------------- phase B: indeg+row_start+dst_norm+CSR fill, all in LDS --------
__global__ __launch_bounds__(512) void k_fill2(const unsigned int* __restrict__ recs_d,
                                               const int* __restrict__ cursor_d,
                                               const int* __restrict__ bucket_base,
                                               int* __restrict__ row_start,
                                               float* __restrict__ dst_norm,
                                               int* __restrict__ csr_src) {
  __shared__ int hist[512];
  __shared__ int lcur[512];
  const int b = blockIdx.x;
  const int t = threadIdx.x;
  hist[t] = 0;
  __syncthreads();
  const int beg = b * BUCKET_CAP;
  const int end = cursor_d[b];
  for (int i = beg + t; i < end; i += 512) atomicAdd(&hist[recs_d[i] & 511], 1);
  __syncthreads();
  int deg = hist[t];
  lcur[t] = deg;
  __syncthreads();
  for (int off = 1; off < 512; off <<= 1) {
    int x = (t >= off) ? lcur[t - off] : 0;
    __syncthreads();
    lcur[t] += x;
    __syncthreads();
  }
  int rs = bucket_base[b] + lcur[t] - deg;
  row_start[b * 512 + t] = rs;
  int dd = deg < 1 ? 1 : deg;
  dst_norm[b * 512 + t] = 1.0f / sqrtf((float)dd);
  lcur[t] = rs;
  __syncthreads();
  for (int i = beg + t; i < end; i += 512) {
    unsigned int r = recs_d[i];
    int p = atomicAdd(&lcur[r & 511], 1);
    csr_src[p] = (int)(r >> BUCKET_SHIFT);
  }
}

// ---------------- GEMM v8: 64-row tile, 8x4 thread tile, 128 threads ------------
// Combines v2's LDS-efficiency (3 b128 / 32 FMA) with v5's occupancy (grid 2048
// = 8 blocks/CU). Thread (tr,tc) computes rows {tr*4+i, 32+tr*4+i} x cols
// tc*4..+3. A-reads: 8 distinct b128 spanning banks 0-31 once + 8-way
// same-address broadcast -> conflict-free. XOR swizzle as v5. Norm in epilogue.
template <int DIN, int DOUT>
__global__ __launch_bounds__(128) void k_gemm_v8(const float* __restrict__ h,
                                                 const float* __restrict__ src_norm,
                                                 const float* __restrict__ W,
                                                 float* __restrict__ out) {
  constexpr int KC   = 32;
  constexpr int ROWS = 64;
  constexpr int HF4  = KC * ROWS / 4;   // 512
  constexpr int WF4  = KC * DOUT / 4;   // 512 for DOUT=64
  __shared__ float hT[KC][ROWS];
  __shared__ float Ws[KC][DOUT];

  const int t  = threadIdx.x;
  const int rowBase = blockIdx.x * ROWS;
  const int tr = t & 7;        // 8 row groups
  const int tc = t >> 3;       // 16 col groups

  float acc[8][4];
#pragma unroll
  for (int i = 0; i < 8; ++i)
#pragma unroll
    for (int j = 0; j < 4; ++j) acc[i][j] = 0.0f;

  for (int kc = 0; kc < DIN; kc += KC) {
    // stage hT (transposed, swizzled writes); 4 float4 per thread
#pragma unroll
    for (int p = 0; p < HF4 / 128; ++p) {
      int f = t + p * 128;
      int rg = f >> 3;
      int ks = (f & 7) * 4;
      float4 v = *reinterpret_cast<const float4*>(&h[(size_t)(rowBase + rg) * DIN + kc + ks]);
      hT[ks + 0][rg ^ ((((ks + 0) >> 3) & 3) << 3)] = v.x;
      hT[ks + 1][rg ^ ((((ks + 1) >> 3) & 3) << 3)] = v.y;
      hT[ks + 2][rg ^ ((((ks + 2) >> 3) & 3) << 3)] = v.z;
      hT[ks + 3][rg ^ ((((ks + 3) >> 3) & 3) << 3)] = v.w;
    }
    // stage Ws; 4 float4 per thread
#pragma unroll
    for (int p = 0; p < WF4 / 128; ++p) {
      int idx = (t + p * 128) * 4;
      *reinterpret_cast<float4*>(&Ws[0][0] + idx) =
          *reinterpret_cast<const float4*>(&W[(size_t)kc * DOUT + idx]);
    }
    __syncthreads();
#pragma unroll
    for (int kk = 0; kk < KC; ++kk) {
      const int swz = ((kk >> 3) & 3) << 3;
      float4 a0 = *reinterpret_cast<const float4*>(&hT[kk][(tr * 4) ^ swz]);
      float4 a1 = *reinterpret_cast<const float4*>(&hT[kk][32 + ((tr * 4) ^ swz)]);
      float4 b  = *reinterpret_cast<const float4*>(&Ws[kk][tc * 4]);
      float av0[4] = {a0.x, a0.y, a0.z, a0.w};
      float av1[4] = {a1.x, a1.y, a1.z, a1.w};
      float bb[4]  = {b.x, b.y, b.z, b.w};
#pragma unroll
      for (int i = 0; i < 4; ++i)
#pragma unroll
        for (int j = 0; j < 4; ++j) {
          acc[i][j]     += av0[i] * bb[j];
          acc[4 + i][j] += av1[i] * bb[j];
        }
    }
    __syncthreads();
  }

#pragma unroll
  for (int half = 0; half < 2; ++half) {
#pragma unroll
    for (int i = 0; i < 4; ++i) {
      int row = rowBase + half * 32 + tr * 4 + i;
      float nrm = src_norm[row];
      float4 v = {acc[half * 4 + i][0] * nrm, acc[half * 4 + i][1] * nrm,
                  acc[half * 4 + i][2] * nrm, acc[half * 4 + i][3] * nrm};
      *reinterpret_cast<float4*>(&out[(size_t)row * DOUT + tc * 4]) = v;
    }
  }
}

// ---------------- GEMM v7 (r13, best for small DIN): lane=row, SGPR B ----------
template <int DIN, int DOUT>
__global__ __launch_bounds__(256) void k_gemm_v7(const float* __restrict__ h,
                                                 const float* __restrict__ src_norm,
                                                 const float* __restrict__ W,
                                                 float* __restrict__ out) {
  constexpr int KC   = 32;
  constexpr int ROWS = 64;
  constexpr int NCH  = DIN / KC;
  constexpr int CPW  = DOUT / 4;     // cols per wave
  __shared__ float hT[KC][ROWS];

  const int t    = threadIdx.x;
  const int lane = t & 63;
  const int wv   = __builtin_amdgcn_readfirstlane(t >> 6);
  const int rowBase = blockIdx.x * ROWS;
  const int rg0 = t >> 3;
  const int ks  = (t & 7) * 4;

  float acc[CPW];
#pragma unroll
  for (int j = 0; j < CPW; ++j) acc[j] = 0.0f;

  for (int ch = 0; ch < NCH; ++ch) {
    const int kc = ch * KC;
#pragma unroll
    for (int p = 0; p < 2; ++p) {
      int rg = rg0 + 32 * p;
      float4 v = *reinterpret_cast<const float4*>(&h[(size_t)(rowBase + rg) * DIN + kc + ks]);
      hT[ks + 0][rg ^ ((((ks + 0) >> 3) & 3) << 3)] = v.x;
      hT[ks + 1][rg ^ ((((ks + 1) >> 3) & 3) << 3)] = v.y;
      hT[ks + 2][rg ^ ((((ks + 2) >> 3) & 3) << 3)] = v.z;
      hT[ks + 3][rg ^ ((((ks + 3) >> 3) & 3) << 3)] = v.w;
    }
    __syncthreads();
    const float* Wrow = &W[(size_t)kc * DOUT + wv * CPW];  // wave-uniform base
#pragma unroll
    for (int kk = 0; kk < KC; ++kk) {
      const int swz = ((kk >> 3) & 3) << 3;
      float a = hT[kk][lane ^ swz];
#pragma unroll
      for (int j = 0; j < CPW; ++j)
        acc[j] += a * Wrow[kk * DOUT + j];   // uniform addr -> s_load
    }
    __syncthreads();
  }

  const int row = rowBase + lane;
  float nrm = src_norm[row];
  float* op = &out[(size_t)row * DOUT + wv * CPW];
#pragma unroll
  for (int q = 0; q < CPW / 4; ++q) {
    float4 v = {acc[q * 4 + 0] * nrm, acc[q * 4 + 1] * nrm,
                acc[q * 4 + 2] * nrm, acc[q * 4 + 3] * nrm};
    *reinterpret_cast<float4*>(op + q * 4) = v;
  }
}

// ---------------- aggregation: float4 gathers, D/4 lanes per node ----------------
template <int D>
__global__ __launch_bounds__(256) void k_agg(const float* __restrict__ hw,
                                             const int* __restrict__ row_start,
                                             const int* __restrict__ csr_src,
                                             const float* __restrict__ dst_norm,
                                             const float* __restrict__ bias,
                                             float* __restrict__ out) {
  constexpr int LPN = D / 4;     // lanes per node
  constexpr int NPW = 64 / LPN;  // nodes per wave
  const int t = threadIdx.x;
  const int lane = t & 63;
  const int wave = t >> 6;
  const int f4  = (lane % LPN) * 4;
  const int sub = lane / LPN;
  const int node = (blockIdx.x * 4 + wave) * NPW + sub;
  const int start = row_start[node];
  const int end   = row_start[node + 1];
  float ax = 0.0f, ay = 0.0f, az = 0.0f, aw = 0.0f;
  int i = start;
  for (; i + 4 <= end; i += 4) {
    int s0 = csr_src[i + 0];
    int s1 = csr_src[i + 1];
    int s2 = csr_src[i + 2];
    int s3 = csr_src[i + 3];
    float4 v0 = *reinterpret_cast<const float4*>(&hw[(size_t)s0 * D + f4]);
    float4 v1 = *reinterpret_cast<const float4*>(&hw[(size_t)s1 * D + f4]);
    float4 v2 = *reinterpret_cast<const float4*>(&hw[(size_t)s2 * D + f4]);
    float4 v3 = *reinterpret_cast<const float4*>(&hw[(size_t)s3 * D + f4]);
    ax += v0.x + v1.x + v2.x + v3.x;
    ay += v0.y + v1.y + v2.y + v3.y;
    az += v0.z + v1.z + v2.z + v3.z;
    aw += v0.w + v1.w + v2.w + v3.w;
  }
  for (; i < end; ++i) {
    float4 v = *reinterpret_cast<const float4*>(&hw[(size_t)csr_src[i] * D + f4]);
    ax += v.x; ay += v.y; az += v.z; aw += v.w;
  }
  float nrm = dst_norm[node];
  float4 b4 = *reinterpret_cast<const float4*>(&bias[f4]);
  float4 r;
  r.x = fmaxf(ax * nrm + b4.x, 0.0f);
  r.y = fmaxf(ay * nrm + b4.y, 0.0f);
  r.z = fmaxf(az * nrm + b4.z, 0.0f);
  r.w = fmaxf(aw * nrm + b4.w, 0.0f);
  *reinterpret_cast<float4*>(&out[(size_t)node * D + f4]) = r;
}

// ---------------- pooling ----------------
__global__ __launch_bounds__(256) void k_pool(const float* __restrict__ h3,
                                              const int* __restrict__ gid,
                                              float* __restrict__ sums,
                                              float* __restrict__ cnt) {
  const int t = threadIdx.x;
  const int f = t & 15;
  const int grp = t >> 4;
  const int base = blockIdx.x * POOL_NPB;
  float acc = 0.0f, c = 0.0f;
  int cur = gid[base + grp];
#pragma unroll 4
  for (int k = 0; k < POOL_NPB / 16; ++k) {
    int node = base + grp + k * 16;
    int g = gid[node];
    float v = h3[(size_t)node * 16 + f];
    if (g != cur) {
      atomicAdd(&sums[cur * 16 + f], acc);
      if (f == 0) atomicAdd(&cnt[cur], c);
      acc = 0.0f; c = 0.0f; cur = g;
    }
    acc += v; c += 1.0f;
  }
  atomicAdd(&sums[cur * 16 + f], acc);
  if (f == 0) atomicAdd(&cnt[cur], c);
}

__global__ __launch_bounds__(128) void k_classify(const float* __restrict__ sums,
                                                  const float* __restrict__ cnt,
                                                  const float* __restrict__ Wc,
                                                  const float* __restrict__ bc,
                                                  float* __restrict__ out) {
  int g = threadIdx.x;
  float c = cnt[g]; if (c < 1.0f) c = 1.0f;
  float acc = 0.0f;
#pragma unroll
  for (int f = 0; f < 16; ++f) acc += (sums[g * 16 + f] / c) * Wc[f];
  out[g] = acc + bc[0];
}

// ---------------- launch ----------------
extern "C" void kernel_launch(void* const* d_in, const int* in_sizes, int n_in,
                              void* d_out, int out_size, void* d_ws, size_t ws_size,
                              hipStream_t stream) {
  const float* features = (const float*)d_in[0];
  const int*   src      = (const int*)d_in[1];
  const int*   dst      = (const int*)d_in[2];
  const int*   gid      = (const int*)d_in[3];
  const float* W0 = (const float*)d_in[4];
  const float* b0 = (const float*)d_in[5];
  const float* W1 = (const float*)d_in[6];
  const float* b1 = (const float*)d_in[7];
  const float* W2 = (const float*)d_in[8];
  const float* b2 = (const float*)d_in[9];
  const float* Wc = (const float*)d_in[10];
  const float* bc = (const float*)d_in[11];
  float* out = (float*)d_out;

  char* w = (char*)d_ws;
  auto alloc = [&](size_t bytes) {
    void* p = (void*)w;
    w += (bytes + 255) & ~(size_t)255;
    return p;
  };
  float* src_norm    = (float*)alloc((size_t)N_NODES * 4);
  float* dst_norm    = (float*)alloc((size_t)N_NODES * 4);
  int*   row_start   = (int*)alloc((size_t)(N_NODES + 1) * 4);
  int*   cursor_d    = (int*)alloc(NB * 4);
  int*   cursor_s    = (int*)alloc(NB * 4);
  int*   bucket_base = (int*)alloc(NB * 4);
  int*   csr_src     = (int*)alloc((size_t)N_EDGES * 4);
  float* buf0        = (float*)alloc((size_t)N_NODES * 64 * 4);
  float* buf1        = (float*)alloc((size_t)N_NODES * 64 * 4);
  float* sums        = (float*)alloc((size_t)N_GRAPHS * 16 * 4);
  float* cnt         = (float*)alloc((size_t)N_GRAPHS * 4);
  unsigned int*   recs_d = (unsigned int*)buf0;
  unsigned short* recs_s = (unsigned short*)buf1;

  hipMemsetAsync(sums, 0, (size_t)(N_GRAPHS * 16 + N_GRAPHS) * 4, stream);

  k_init_buckets<<<1, 256, 0, stream>>>(cursor_d, cursor_s);
  k_bin<<<N_EDGES / (256 * BIN_EPT), 256, 0, stream>>>(src, dst, cursor_d, cursor_s,
                                                       recs_d, recs_s);
  k_outdeg<<<NB, 512, 0, stream>>>(recs_s, cursor_s, src_norm);
  k_bucket_scan<<<1, 256, 0, stream>>>(cursor_d, bucket_base, row_start);
  k_fill2<<<NB, 512, 0, stream>>>(recs_d, cursor_d, bucket_base, row_start,
                                  dst_norm, csr_src);

  // layer 0: 256 -> 64 (v8: v2's LDS ratio + v5's occupancy)
  k_gemm_v8<256, 64><<<N_NODES / 64, 128, 0, stream>>>(features, src_norm, W0, buf0);
  k_agg<64><<<N_NODES / 16, 256, 0, stream>>>(buf0, row_start, csr_src, dst_norm, b0, buf1);
  // layer 1: 64 -> 32 (v7: proven best for small DIN)
  k_gemm_v7<64, 32><<<N_NODES / 64, 256, 0, stream>>>(buf1, src_norm, W1, buf0);
  k_agg<32><<<N_NODES / 32, 256, 0, stream>>>(buf0, row_start, csr_src, dst_norm, b1, buf1);
  // layer 2: 32 -> 16 (v7)
  k_gemm_v7<32, 16><<<N_NODES / 64, 256, 0, stream>>>(buf1, src_norm, W2, buf0);
  k_agg<16><<<N_NODES / 64, 256, 0, stream>>>(buf0, row_start, csr_src, dst_norm, b2, buf1);

  k_pool<<<N_NODES / POOL_NPB, 256, 0, stream>>>(buf1, gid, sums, cnt);
  k_classify<<<1, 128, 0, stream>>>(sums, cnt, Wc, bc, out);
}

// Round 16
// 333.824 us; speedup vs baseline: 1.1828x; 1.0018x over previous
//
#include <hip/hip_runtime.h>

#define N_NODES 131072
#define N_EDGES 2097152
#define N_GRAPHS 128
#define POOL_NPB 256       // nodes per block in k_pool
#define NB 256             // buckets (both src- and dst-binning)
#define BUCKET_SHIFT 9     // 512 nodes per bucket
#define BUCKET_CAP 9728    // max edges per bucket (mean 8192, +17 sigma)
#define BIN_EPT 32         // edges per thread per pass in k_bin (8192/block)

// ---------------- bucket cursor init ----------------
__global__ __launch_bounds__(256) void k_init_buckets(int* __restrict__ cursor_d,
                                                      int* __restrict__ cursor_s) {
  int i = threadIdx.x;
  cursor_d[i] = i * BUCKET_CAP;
  cursor_s[i] = i * BUCKET_CAP;
}

// ---------------- phase A: bin edges (two-pass, zero per-edge global atomics) ----
__global__ __launch_bounds__(256) void k_bin(const int* __restrict__ src,
                                             const int* __restrict__ dst,
                                             int* __restrict__ cursor_d,
                                             int* __restrict__ cursor_s,
                                             unsigned int* __restrict__ recs_d,
                                             unsigned short* __restrict__ recs_s) {
  __shared__ int hd[NB];
  __shared__ int hs[NB];
  const int t = threadIdx.x;
  const int e0 = blockIdx.x * (256 * BIN_EPT);
  hd[t] = 0; hs[t] = 0;
  __syncthreads();
#pragma unroll 4
  for (int k = 0; k < BIN_EPT; ++k) {
    int e = e0 + k * 256 + t;
    atomicAdd(&hd[dst[e] >> BUCKET_SHIFT], 1);
    atomicAdd(&hs[src[e] >> BUCKET_SHIFT], 1);
  }
  __syncthreads();
  { int c = hd[t]; hd[t] = c ? atomicAdd(&cursor_d[t], c) : 0; }
  { int c = hs[t]; hs[t] = c ? atomicAdd(&cursor_s[t], c) : 0; }
  __syncthreads();
#pragma unroll 4
  for (int k = 0; k < BIN_EPT; ++k) {
    int e = e0 + k * 256 + t;      // re-read (L2/L3 hot)
    int s = src[e];
    int d = dst[e];
    int pd = atomicAdd(&hd[d >> BUCKET_SHIFT], 1);
    recs_d[pd] = ((unsigned int)s << BUCKET_SHIFT) | (unsigned int)(d & 511);
    int ps = atomicAdd(&hs[s >> BUCKET_SHIFT], 1);
    recs_s[ps] = (unsigned short)(s & 511);
  }
}

// ---------------- outdeg via LDS histogram -> src_norm ----------------
__global__ __launch_bounds__(512) void k_outdeg(const unsigned short* __restrict__ recs_s,
                                                const int* __restrict__ cursor_s,
                                                float* __restrict__ src_norm) {
  __shared__ int hist[512];
  const int b = blockIdx.x;
  const int t = threadIdx.x;
  hist[t] = 0;
  __syncthreads();
  const int beg = b * BUCKET_CAP;
  const int end = cursor_s[b];
  for (int i = beg + t; i < end; i += 512) atomicAdd(&hist[recs_s[i]], 1);
  __syncthreads();
  int od = hist[t]; if (od < 1) od = 1;
  src_norm[b * 512 + t] = 1.0f / sqrtf((float)od);
}

// ---------------- bucket base: exclusive scan of dst-bucket counts ----------------
__global__ __launch_bounds__(256) void k_bucket_scan(const int* __restrict__ cursor_d,
                                                     int* __restrict__ bucket_base,
                                                     int* __restrict__ row_start) {
  __shared__ int tmp[256];
  int t = threadIdx.x;
  int c = cursor_d[t] - t * BUCKET_CAP;
  tmp[t] = c;
  __syncthreads();
  for (int off = 1; off < 256; off <<= 1) {
    int x = (t >= off) ? tmp[t - off] : 0;
    __syncthreads();
    tmp[t] += x;
    __syncthreads();
  }
  bucket_base[t] = tmp[t] - c;
  if (t == 0) row_start[N_NODES] = N_EDGES;
}

// ---------------- phase B: indeg+row_start+dst_norm+CSR fill, all in LDS --------
__global__ __launch_bounds__(512) void k_fill2(const unsigned int* __restrict__ recs_d,
                                               const int* __restrict__ cursor_d,
                                               const int* __restrict__ bucket_base,
                                               int* __restrict__ row_start,
                                               float* __restrict__ dst_norm,
                                               int* __restrict__ csr_src) {
  __shared__ int hist[512];
  __shared__ int lcur[512];
  const int b = blockIdx.x;
  const int t = threadIdx.x;
  hist[t] = 0;
  __syncthreads();
  const int beg = b * BUCKET_CAP;
  const int end = cursor_d[b];
  for (int i = beg + t; i < end; i += 512) atomicAdd(&hist[recs_d[i] & 511], 1);
  __syncthreads();
  int deg = hist[t];
  lcur[t] = deg;
  __syncthreads();
  for (int off = 1; off < 512; off <<= 1) {
    int x = (t >= off) ? lcur[t - off] : 0;
    __syncthreads();
    lcur[t] += x;
    __syncthreads();
  }
  int rs = bucket_base[b] + lcur[t] - deg;
  row_start[b * 512 + t] = rs;
  int dd = deg < 1 ? 1 : deg;
  dst_norm[b * 512 + t] = 1.0f / sqrtf((float)dd);
  lcur[t] = rs;
  __syncthreads();
  for (int i = beg + t; i < end; i += 512) {
    unsigned int r = recs_d[i];
    int p = atomicAdd(&lcur[r & 511], 1);
    csr_src[p] = (int)(r >> BUCKET_SHIFT);
  }
}

// ---------------- GEMM v9: 8x8 register tile, 1-wave blocks ---------------------
// LDS-pipe model (m134: b128 ~12cyc/instr/CU): time = VALU_floor * 12/T for TxT
// tile. T=4 (v5/v8) = 2-3x floor; T=8 -> 1.5x (~41us + staging). r12's 8x8
// failed on occupancy (128-thr blocks / small grid); here: 64-thr (1-wave)
// blocks, ROWS=64, grid 2048 = 8 blocks/CU, LDS 16KB (128KB/CU). Thread (tr,tc)
// computes rows {tr*4+i, 32+tr*4+i} x cols tc*8..+7. A-reads: 8 distinct b128
// covering banks 0-31 once, 8-way broadcast -> free. XOR swizzle as v5.
template <int DIN, int DOUT>
__global__ __launch_bounds__(64) void k_gemm_v9(const float* __restrict__ h,
                                                const float* __restrict__ src_norm,
                                                const float* __restrict__ W,
                                                float* __restrict__ out) {
  constexpr int KC   = 32;
  constexpr int ROWS = 64;
  constexpr int HF4  = KC * ROWS / 4;   // 512 float4s
  constexpr int WF4  = KC * DOUT / 4;   // 512 float4s (DOUT=64)
  __shared__ float hT[KC][ROWS];
  __shared__ float Ws[KC][DOUT];

  const int t  = threadIdx.x;
  const int rowBase = blockIdx.x * ROWS;
  const int tr = t & 7;        // 8 row groups
  const int tc = t >> 3;       // 8 col groups

  float acc[8][8];
#pragma unroll
  for (int i = 0; i < 8; ++i)
#pragma unroll
    for (int j = 0; j < 8; ++j) acc[i][j] = 0.0f;

  for (int kc = 0; kc < DIN; kc += KC) {
    // stage hT (transposed, swizzled writes); 8 float4 per thread
#pragma unroll
    for (int p = 0; p < HF4 / 64; ++p) {
      int f = t + p * 64;
      int rg = f >> 3;
      int ks = (f & 7) * 4;
      float4 v = *reinterpret_cast<const float4*>(&h[(size_t)(rowBase + rg) * DIN + kc + ks]);
      hT[ks + 0][rg ^ ((((ks + 0) >> 3) & 3) << 3)] = v.x;
      hT[ks + 1][rg ^ ((((ks + 1) >> 3) & 3) << 3)] = v.y;
      hT[ks + 2][rg ^ ((((ks + 2) >> 3) & 3) << 3)] = v.z;
      hT[ks + 3][rg ^ ((((ks + 3) >> 3) & 3) << 3)] = v.w;
    }
    // stage Ws; 8 float4 per thread
#pragma unroll
    for (int p = 0; p < WF4 / 64; ++p) {
      int idx = (t + p * 64) * 4;
      *reinterpret_cast<float4*>(&Ws[0][0] + idx) =
          *reinterpret_cast<const float4*>(&W[(size_t)kc * DOUT + idx]);
    }
    __syncthreads();
#pragma unroll
    for (int kk = 0; kk < KC; ++kk) {
      const int swz = ((kk >> 3) & 3) << 3;
      float4 a0 = *reinterpret_cast<const float4*>(&hT[kk][(tr * 4) ^ swz]);
      float4 a1 = *reinterpret_cast<const float4*>(&hT[kk][32 + ((tr * 4) ^ swz)]);
      float4 b0 = *reinterpret_cast<const float4*>(&Ws[kk][tc * 8]);
      float4 b1 = *reinterpret_cast<const float4*>(&Ws[kk][tc * 8 + 4]);
      float av0[4] = {a0.x, a0.y, a0.z, a0.w};
      float av1[4] = {a1.x, a1.y, a1.z, a1.w};
      float bb[8]  = {b0.x, b0.y, b0.z, b0.w, b1.x, b1.y, b1.z, b1.w};
#pragma unroll
      for (int i = 0; i < 4; ++i)
#pragma unroll
        for (int j = 0; j < 8; ++j) {
          acc[i][j]     += av0[i] * bb[j];
          acc[4 + i][j] += av1[i] * bb[j];
        }
    }
    __syncthreads();
  }

#pragma unroll
  for (int half = 0; half < 2; ++half) {
#pragma unroll
    for (int i = 0; i < 4; ++i) {
      int row = rowBase + half * 32 + tr * 4 + i;
      float nrm = src_norm[row];
      float* op = &out[(size_t)row * DOUT + tc * 8];
      float4 v0 = {acc[half * 4 + i][0] * nrm, acc[half * 4 + i][1] * nrm,
                   acc[half * 4 + i][2] * nrm, acc[half * 4 + i][3] * nrm};
      float4 v1 = {acc[half * 4 + i][4] * nrm, acc[half * 4 + i][5] * nrm,
                   acc[half * 4 + i][6] * nrm, acc[half * 4 + i][7] * nrm};
      *reinterpret_cast<float4*>(op)     = v0;
      *reinterpret_cast<float4*>(op + 4) = v1;
    }
  }
}

// ---------------- GEMM v7 (r13, best for small DIN): lane=row, SGPR B ----------
template <int DIN, int DOUT>
__global__ __launch_bounds__(256) void k_gemm_v7(const float* __restrict__ h,
                                                 const float* __restrict__ src_norm,
                                                 const float* __restrict__ W,
                                                 float* __restrict__ out) {
  constexpr int KC   = 32;
  constexpr int ROWS = 64;
  constexpr int NCH  = DIN / KC;
  constexpr int CPW  = DOUT / 4;     // cols per wave
  __shared__ float hT[KC][ROWS];

  const int t    = threadIdx.x;
  const int lane = t & 63;
  const int wv   = __builtin_amdgcn_readfirstlane(t >> 6);
  const int rowBase = blockIdx.x * ROWS;
  const int rg0 = t >> 3;
  const int ks  = (t & 7) * 4;

  float acc[CPW];
#pragma unroll
  for (int j = 0; j < CPW; ++j) acc[j] = 0.0f;

  for (int ch = 0; ch < NCH; ++ch) {
    const int kc = ch * KC;
#pragma unroll
    for (int p = 0; p < 2; ++p) {
      int rg = rg0 + 32 * p;
      float4 v = *reinterpret_cast<const float4*>(&h[(size_t)(rowBase + rg) * DIN + kc + ks]);
      hT[ks + 0][rg ^ ((((ks + 0) >> 3) & 3) << 3)] = v.x;
      hT[ks + 1][rg ^ ((((ks + 1) >> 3) & 3) << 3)] = v.y;
      hT[ks + 2][rg ^ ((((ks + 2) >> 3) & 3) << 3)] = v.z;
      hT[ks + 3][rg ^ ((((ks + 3) >> 3) & 3) << 3)] = v.w;
    }
    __syncthreads();
    const float* Wrow = &W[(size_t)kc * DOUT + wv * CPW];  // wave-uniform base
#pragma unroll
    for (int kk = 0; kk < KC; ++kk) {
      const int swz = ((kk >> 3) & 3) << 3;
      float a = hT[kk][lane ^ swz];
#pragma unroll
      for (int j = 0; j < CPW; ++j)
        acc[j] += a * Wrow[kk * DOUT + j];   // uniform addr -> s_load
    }
    __syncthreads();
  }

  const int row = rowBase + lane;
  float nrm = src_norm[row];
  float* op = &out[(size_t)row * DOUT + wv * CPW];
#pragma unroll
  for (int q = 0; q < CPW / 4; ++q) {
    float4 v = {acc[q * 4 + 0] * nrm, acc[q * 4 + 1] * nrm,
                acc[q * 4 + 2] * nrm, acc[q * 4 + 3] * nrm};
    *reinterpret_cast<float4*>(op + q * 4) = v;
  }
}

// ---------------- aggregation: float4 gathers, D/4 lanes per node ----------------
template <int D>
__global__ __launch_bounds__(256) void k_agg(const float* __restrict__ hw,
                                             const int* __restrict__ row_start,
                                             const int* __restrict__ csr_src,
                                             const float* __restrict__ dst_norm,
                                             const float* __restrict__ bias,
                                             float* __restrict__ out) {
  constexpr int LPN = D / 4;     // lanes per node
  constexpr int NPW = 64 / LPN;  // nodes per wave
  const int t = threadIdx.x;
  const int lane = t & 63;
  const int wave = t >> 6;
  const int f4  = (lane % LPN) * 4;
  const int sub = lane / LPN;
  const int node = (blockIdx.x * 4 + wave) * NPW + sub;
  const int start = row_start[node];
  const int end   = row_start[node + 1];
  float ax = 0.0f, ay = 0.0f, az = 0.0f, aw = 0.0f;
  int i = start;
  for (; i + 4 <= end; i += 4) {
    int s0 = csr_src[i + 0];
    int s1 = csr_src[i + 1];
    int s2 = csr_src[i + 2];
    int s3 = csr_src[i + 3];
    float4 v0 = *reinterpret_cast<const float4*>(&hw[(size_t)s0 * D + f4]);
    float4 v1 = *reinterpret_cast<const float4*>(&hw[(size_t)s1 * D + f4]);
    float4 v2 = *reinterpret_cast<const float4*>(&hw[(size_t)s2 * D + f4]);
    float4 v3 = *reinterpret_cast<const float4*>(&hw[(size_t)s3 * D + f4]);
    ax += v0.x + v1.x + v2.x + v3.x;
    ay += v0.y + v1.y + v2.y + v3.y;
    az += v0.z + v1.z + v2.z + v3.z;
    aw += v0.w + v1.w + v2.w + v3.w;
  }
  for (; i < end; ++i) {
    float4 v = *reinterpret_cast<const float4*>(&hw[(size_t)csr_src[i] * D + f4]);
    ax += v.x; ay += v.y; az += v.z; aw += v.w;
  }
  float nrm = dst_norm[node];
  float4 b4 = *reinterpret_cast<const float4*>(&bias[f4]);
  float4 r;
  r.x = fmaxf(ax * nrm + b4.x, 0.0f);
  r.y = fmaxf(ay * nrm + b4.y, 0.0f);
  r.z = fmaxf(az * nrm + b4.z, 0.0f);
  r.w = fmaxf(aw * nrm + b4.w, 0.0f);
  *reinterpret_cast<float4*>(&out[(size_t)node * D + f4]) = r;
}

// ---------------- pooling ----------------
__global__ __launch_bounds__(256) void k_pool(const float* __restrict__ h3,
                                              const int* __restrict__ gid,
                                              float* __restrict__ sums,
                                              float* __restrict__ cnt) {
  const int t = threadIdx.x;
  const int f = t & 15;
  const int grp = t >> 4;
  const int base = blockIdx.x * POOL_NPB;
  float acc = 0.0f, c = 0.0f;
  int cur = gid[base + grp];
#pragma unroll 4
  for (int k = 0; k < POOL_NPB / 16; ++k) {
    int node = base + grp + k * 16;
    int g = gid[node];
    float v = h3[(size_t)node * 16 + f];
    if (g != cur) {
      atomicAdd(&sums[cur * 16 + f], acc);
      if (f == 0) atomicAdd(&cnt[cur], c);
      acc = 0.0f; c = 0.0f; cur = g;
    }
    acc += v; c += 1.0f;
  }
  atomicAdd(&sums[cur * 16 + f], acc);
  if (f == 0) atomicAdd(&cnt[cur], c);
}

__global__ __launch_bounds__(128) void k_classify(const float* __restrict__ sums,
                                                  const float* __restrict__ cnt,
                                                  const float* __restrict__ Wc,
                                                  const float* __restrict__ bc,
                                                  float* __restrict__ out) {
  int g = threadIdx.x;
  float c = cnt[g]; if (c < 1.0f) c = 1.0f;
  float acc = 0.0f;
#pragma unroll
  for (int f = 0; f < 16; ++f) acc += (sums[g * 16 + f] / c) * Wc[f];
  out[g] = acc + bc[0];
}

// ---------------- launch ----------------
extern "C" void kernel_launch(void* const* d_in, const int* in_sizes, int n_in,
                              void* d_out, int out_size, void* d_ws, size_t ws_size,
                              hipStream_t stream) {
  const float* features = (const float*)d_in[0];
  const int*   src      = (const int*)d_in[1];
  const int*   dst      = (const int*)d_in[2];
  const int*   gid      = (const int*)d_in[3];
  const float* W0 = (const float*)d_in[4];
  const float* b0 = (const float*)d_in[5];
  const float* W1 = (const float*)d_in[6];
  const float* b1 = (const float*)d_in[7];
  const float* W2 = (const float*)d_in[8];
  const float* b2 = (const float*)d_in[9];
  const float* Wc = (const float*)d_in[10];
  const float* bc = (const float*)d_in[11];
  float* out = (float*)d_out;

  char* w = (char*)d_ws;
  auto alloc = [&](size_t bytes) {
    void* p = (void*)w;
    w += (bytes + 255) & ~(size_t)255;
    return p;
  };
  float* src_norm    = (float*)alloc((size_t)N_NODES * 4);
  float* dst_norm    = (float*)alloc((size_t)N_NODES * 4);
  int*   row_start   = (int*)alloc((size_t)(N_NODES + 1) * 4);
  int*   cursor_d    = (int*)alloc(NB * 4);
  int*   cursor_s    = (int*)alloc(NB * 4);
  int*   bucket_base = (int*)alloc(NB * 4);
  int*   csr_src     = (int*)alloc((size_t)N_EDGES * 4);
  float* buf0        = (float*)alloc((size_t)N_NODES * 64 * 4);
  float* buf1        = (float*)alloc((size_t)N_NODES * 64 * 4);
  float* sums        = (float*)alloc((size_t)N_GRAPHS * 16 * 4);
  float* cnt         = (float*)alloc((size_t)N_GRAPHS * 4);
  unsigned int*   recs_d = (unsigned int*)buf0;
  unsigned short* recs_s = (unsigned short*)buf1;

  hipMemsetAsync(sums, 0, (size_t)(N_GRAPHS * 16 + N_GRAPHS) * 4, stream);

  k_init_buckets<<<1, 256, 0, stream>>>(cursor_d, cursor_s);
  k_bin<<<N_EDGES / (256 * BIN_EPT), 256, 0, stream>>>(src, dst, cursor_d, cursor_s,
                                                       recs_d, recs_s);
  k_outdeg<<<NB, 512, 0, stream>>>(recs_s, cursor_s, src_norm);
  k_bucket_scan<<<1, 256, 0, stream>>>(cursor_d, bucket_base, row_start);
  k_fill2<<<NB, 512, 0, stream>>>(recs_d, cursor_d, bucket_base, row_start,
                                  dst_norm, csr_src);

  // layer 0: 256 -> 64 (v9: 8x8 tile, 1-wave blocks, grid 2048)
  k_gemm_v9<256, 64><<<N_NODES / 64, 64, 0, stream>>>(features, src_norm, W0, buf0);
  k_agg<64><<<N_NODES / 16, 256, 0, stream>>>(buf0, row_start, csr_src, dst_norm, b0, buf1);
  // layer 1: 64 -> 32 (v7: proven best for small DIN)
  k_gemm_v7<64, 32><<<N_NODES / 64, 256, 0, stream>>>(buf1, src_norm, W1, buf0);
  k_agg<32><<<N_NODES / 32, 256, 0, stream>>>(buf0, row_start, csr_src, dst_norm, b1, buf1);
  // layer 2: 32 -> 16 (v7)
  k_gemm_v7<32, 16><<<N_NODES / 64, 256, 0, stream>>>(buf1, src_norm, W2, buf0);
  k_agg<16><<<N_NODES / 64, 256, 0, stream>>>(buf0, row_start, csr_src, dst_norm, b2, buf1);

  k_pool<<<N_NODES / POOL_NPB, 256, 0, stream>>>(buf1, gid, sums, cnt);
  k_classify<<<1, 128, 0, stream>>>(sums, cnt, Wc, bc, out);
}